// Round 1
// baseline (543.964 us; speedup 1.0000x reference)
//
#include <hip/hip_runtime.h>
#include <math.h>

#define NG 4096
#define M 50
#define KTOP 30
#define H 32
#define F_IN 128
#define EPG 400          // edges per graph (M * DEG)
#define E_TOTAL (NG * EPG)
#define DLAT 97
#define LATS 100         // padded stride for lat tile
#define NTHREADS 256

// -------- GCN layer helpers ----------------------------------------------
// matmul: tbuf[i][j] = sum_k hin[i*istride+k] * W[k*H+j]
// thread (iset = tid>>5, j = tid&31) owns rows {iset, iset+8, ..., iset+48}
template <int KIN>
__device__ __forceinline__ void gcn_matmul(const float* __restrict__ hin, int istride,
                                           const float* __restrict__ W,
                                           float (*tbuf)[H], int tid) {
    const int j = tid & 31, iset = tid >> 5;
    float acc[7];
#pragma unroll
    for (int r = 0; r < 7; r++) acc[r] = 0.f;
    for (int k = 0; k < KIN; k++) {
        float w = W[k * H + j];
#pragma unroll
        for (int r = 0; r < 7; r++) {
            int i = iset + r * 8;
            if (i >= M) i = M - 1;            // clamp: row 49 recomputed, write guarded
            acc[r] += hin[i * istride + k] * w;
        }
    }
#pragma unroll
    for (int r = 0; r < 7; r++) {
        int i = iset + r * 8;
        if (i < M) tbuf[i][j] = acc[r];
    }
}

// aggregation + bias + tanh -> lat[:, col0:col0+32]
__device__ __forceinline__ void gcn_agg(const float (*tbuf)[H], const float* __restrict__ b,
                                        float (*lat)[LATS], int col0,
                                        const float* dinv, const int* csr_off,
                                        const int* csr_src, const float* csr_nrm, int tid) {
    const int j = tid & 31, iset = tid >> 5;
    for (int i = iset; i < M; i += 8) {
        float acc = tbuf[i][j] * dinv[i] * dinv[i];   // self loop: norm = 1/deg
        int e0 = csr_off[i], e1 = csr_off[i + 1];
        for (int e = e0; e < e1; e++)
            acc += tbuf[csr_src[e]][j] * csr_nrm[e];
        lat[i][col0 + j] = tanhf(acc + b[j]);
    }
}

__global__ __launch_bounds__(NTHREADS, 2)
void dgcnn_kernel(const float* __restrict__ x, const int* __restrict__ eidx,
                  const float* __restrict__ W0, const float* __restrict__ b0,
                  const float* __restrict__ W1, const float* __restrict__ b1,
                  const float* __restrict__ W2, const float* __restrict__ b2,
                  const float* __restrict__ W3, const float* __restrict__ b3,
                  const float* __restrict__ C1w, const float* __restrict__ C1b,
                  const float* __restrict__ C2w, const float* __restrict__ C2b,
                  const float* __restrict__ L1w, const float* __restrict__ L1b,
                  const float* __restrict__ L2w, const float* __restrict__ L2b,
                  float* __restrict__ out) {
    // xs (layer-1 input) is dead after layer-1 matmul; the post-GCN tail buffers
    // union with it to keep static LDS < 64 KB (total ~59.4 KB -> 2 blocks/CU).
    __shared__ union U {
        float xs[M][F_IN];
        struct {
            float z1[16][KTOP];
            float pbuf[16][15];
            float z2[352];
            float d1[128];
            float red[128];
            int   ord[M];
        } post;
    } u;
    __shared__ float lat[M][LATS];        // h1|h2|h3|h4 concat, padded stride
    __shared__ float tbuf[M][H];          // pre-aggregation h@W
    __shared__ float deg[M], dinv[M];
    __shared__ int   ls[EPG], ld[EPG];
    __shared__ float nrm[EPG];
    __shared__ int   csr_off[M + 1], cursor[M];
    __shared__ int   csr_src[EPG];
    __shared__ float csr_nrm[EPG];

    const int g = blockIdx.x;
    const int tid = threadIdx.x;
    const int nbase = g * M;
    const int ebase = g * EPG;

    // ---- load x tile ----
    for (int idx = tid; idx < M * F_IN; idx += NTHREADS)
        ((float*)u.xs)[idx] = x[nbase * F_IN + idx];

    // ---- degrees (in-degree + self loop) ----
    if (tid < M) deg[tid] = 1.0f;
    __syncthreads();
    for (int e = tid; e < EPG; e += NTHREADS) {
        int s = eidx[ebase + e] - nbase;
        int d = eidx[E_TOTAL + ebase + e] - nbase;
        ls[e] = s; ld[e] = d;
        atomicAdd(&deg[d], 1.0f);
    }
    __syncthreads();
    if (tid < M) dinv[tid] = 1.0f / sqrtf(deg[tid]);
    __syncthreads();
    for (int e = tid; e < EPG; e += NTHREADS)
        nrm[e] = dinv[ls[e]] * dinv[ld[e]];   // read back by same thread only

    // ---- CSR by dst (built once, reused by all 4 layers) ----
    if (tid == 0) {
        int acc = 0;
        for (int i = 0; i < M; i++) {
            csr_off[i] = acc; cursor[i] = acc;
            acc += (int)deg[i] - 1;
        }
        csr_off[M] = acc;
    }
    __syncthreads();
    for (int e = tid; e < EPG; e += NTHREADS) {
        int pos = atomicAdd(&cursor[ld[e]], 1);
        csr_src[pos] = ls[e];
        csr_nrm[pos] = nrm[e];
    }
    __syncthreads();

    // ---- GCN layer 1: x[50,128] -> lat[:,0:32] ----
    gcn_matmul<F_IN>(&u.xs[0][0], F_IN, W0, tbuf, tid);
    __syncthreads();
    gcn_agg(tbuf, b0, lat, 0, dinv, csr_off, csr_src, csr_nrm, tid);
    __syncthreads();
    // ---- layer 2: lat[:,0:32] -> lat[:,32:64] ----
    gcn_matmul<H>(&lat[0][0], LATS, W1, tbuf, tid);
    __syncthreads();
    gcn_agg(tbuf, b1, lat, 32, dinv, csr_off, csr_src, csr_nrm, tid);
    __syncthreads();
    // ---- layer 3: lat[:,32:64] -> lat[:,64:96] ----
    gcn_matmul<H>(&lat[0][32], LATS, W2, tbuf, tid);
    __syncthreads();
    gcn_agg(tbuf, b2, lat, 64, dinv, csr_off, csr_src, csr_nrm, tid);
    __syncthreads();
    // ---- layer 4 (H -> 1): lat[:,64:96] -> lat[:,96] ----
    if (tid < M) {
        float acc = 0.f;
        for (int k = 0; k < H; k++) acc += lat[tid][64 + k] * W3[k];
        tbuf[tid][0] = acc;
    }
    __syncthreads();
    if (tid < M) {
        float acc = tbuf[tid][0] * dinv[tid] * dinv[tid];
        int e0 = csr_off[tid], e1 = csr_off[tid + 1];
        for (int e = e0; e < e1; e++)
            acc += tbuf[csr_src[e]][0] * csr_nrm[e];
        lat[tid][96] = tanhf(acc + b3[0]);
    }
    __syncthreads();

    // ---- sort-pool: stable descending rank over lat[:,96] ----
    if (tid < M) {
        float v = lat[tid][96];
        int r = 0;
        for (int jj = 0; jj < M; jj++) {
            float vj = lat[jj][96];
            r += (vj > v) || (vj == v && jj < tid);
        }
        u.post.ord[r] = tid;
    }
    __syncthreads();

    // ---- Conv1d(1,16,97,stride 97) + ReLU: z1[c][t] ----
    for (int idx = tid; idx < 16 * KTOP; idx += NTHREADS) {
        int c = idx / KTOP, t = idx - c * KTOP;
        const float* row = lat[u.post.ord[t]];
        float acc = 0.f;
        for (int d = 0; d < DLAT; d++) acc += row[d] * C1w[c * DLAT + d];
        acc += C1b[c];
        u.post.z1[c][t] = fmaxf(acc, 0.f);
    }
    __syncthreads();

    // ---- MaxPool1d(2,2): p[c][u] ----
    for (int idx = tid; idx < 16 * 15; idx += NTHREADS) {
        int c = idx / 15, t = idx - c * 15;
        u.post.pbuf[c][t] = fmaxf(u.post.z1[c][2 * t], u.post.z1[c][2 * t + 1]);
    }
    __syncthreads();

    // ---- Conv1d(16,32,5) + ReLU, flatten f = o*11 + t ----
    for (int idx = tid; idx < 352; idx += NTHREADS) {
        int o = idx / 11, t = idx - o * 11;
        float acc = C2b[o];
        for (int i = 0; i < 16; i++) {
#pragma unroll
            for (int k = 0; k < 5; k++)
                acc += u.post.pbuf[i][t + k] * C2w[(o * 16 + i) * 5 + k];
        }
        u.post.z2[idx] = fmaxf(acc, 0.f);
    }
    __syncthreads();

    // ---- Dense 352 -> 128 + ReLU ----
    if (tid < 128) {
        float acc = L1b[tid];
        for (int f = 0; f < 352; f++) acc += u.post.z2[f] * L1w[f * 128 + tid];
        u.post.d1[tid] = fmaxf(acc, 0.f);
    }
    __syncthreads();

    // ---- Dense 128 -> 1 ----
    if (tid < 128) u.post.red[tid] = u.post.d1[tid] * L2w[tid];
    __syncthreads();
    if (tid < 64) u.post.red[tid] += u.post.red[tid + 64];
    __syncthreads();
    if (tid == 0) {
        float s = 0.f;
        for (int i = 0; i < 64; i++) s += u.post.red[i];
        out[g] = s + L2b[0];
    }
}

extern "C" void kernel_launch(void* const* d_in, const int* in_sizes, int n_in,
                              void* d_out, int out_size, void* d_ws, size_t ws_size,
                              hipStream_t stream) {
    const float* x    = (const float*)d_in[0];
    const int*   eidx = (const int*)d_in[1];
    // d_in[2] (batch) unused: graphs are contiguous equal-size blocks
    dgcnn_kernel<<<NG, NTHREADS, 0, stream>>>(
        x, eidx,
        (const float*)d_in[3],  (const float*)d_in[4],
        (const float*)d_in[5],  (const float*)d_in[6],
        (const float*)d_in[7],  (const float*)d_in[8],
        (const float*)d_in[9],  (const float*)d_in[10],
        (const float*)d_in[11], (const float*)d_in[12],
        (const float*)d_in[13], (const float*)d_in[14],
        (const float*)d_in[15], (const float*)d_in[16],
        (const float*)d_in[17], (const float*)d_in[18],
        (float*)d_out);
}

// Round 2
// 428.199 us; speedup vs baseline: 1.2704x; 1.2704x over previous
//
#include <hip/hip_runtime.h>
#include <math.h>

#define NG 4096
#define M 50
#define KTOP 30
#define H 32
#define F_IN 128
#define EPG 400          // edges per graph (M * DEG)
#define E_TOTAL (NG * EPG)
#define DLAT 97
#define LATS 100         // padded stride for lat tile
#define NTHREADS 256

// -------- GCN matmul ------------------------------------------------------
// tbuf[i][j] = sum_k hin[i*istride+k] * W[k*H+j]
// thread (iset = tid>>5, j = tid&31) owns rows {iset, iset+8, ..., iset+48}.
// hin may be global (layer 1: x) or LDS (layers 2/3: lat); istride % 4 == 0
// and 16B base alignment let us read float4 (global_load_dwordx4 /
// ds_read_b128). W is read from global (4KB..16KB, L1/L2-hot: same addresses
// for every block; same address across the 32 j... no — consecutive j lanes
// coalesce, two isets per wave broadcast).
template <int KIN>
__device__ __forceinline__ void gcn_matmul(const float* hin, int istride,
                                           const float* __restrict__ W,
                                           float (*tb)[H], int tid) {
    const int j = tid & 31, iset = tid >> 5;
    float acc[7];
    int rows[7];
#pragma unroll
    for (int r = 0; r < 7; r++) {
        acc[r] = 0.f;
        int i = iset + r * 8;
        rows[r] = (i >= M) ? (M - 1) : i;   // clamp: row 49 recomputed, store guarded
    }
#pragma unroll 2
    for (int k4 = 0; k4 < KIN / 4; k4++) {
        const float w0 = W[(4 * k4 + 0) * H + j];
        const float w1 = W[(4 * k4 + 1) * H + j];
        const float w2 = W[(4 * k4 + 2) * H + j];
        const float w3 = W[(4 * k4 + 3) * H + j];
#pragma unroll
        for (int r = 0; r < 7; r++) {
            const float4 xv = *(const float4*)(hin + rows[r] * istride + 4 * k4);
            acc[r] += xv.x * w0 + xv.y * w1 + xv.z * w2 + xv.w * w3;
        }
    }
#pragma unroll
    for (int r = 0; r < 7; r++) {
        int i = iset + r * 8;
        if (i < M) tb[i][j] = acc[r];
    }
}

// aggregation + bias + tanh -> lat[:, col0:col0+32]
__device__ __forceinline__ void gcn_agg(const float (*tbuf)[H], const float* __restrict__ b,
                                        float (*lat)[LATS], int col0,
                                        const float* dinv, const int* csr_off,
                                        const int* csr_src, const float* csr_nrm, int tid) {
    const int j = tid & 31, iset = tid >> 5;
    for (int i = iset; i < M; i += 8) {
        float acc = tbuf[i][j] * dinv[i] * dinv[i];   // self loop: norm = 1/deg
        int e0 = csr_off[i], e1 = csr_off[i + 1];
        for (int e = e0; e < e1; e++)
            acc += tbuf[csr_src[e]][j] * csr_nrm[e];
        lat[i][col0 + j] = tanhf(acc + b[j]);
    }
}

__global__ __launch_bounds__(NTHREADS, 4)
void dgcnn_kernel(const float* __restrict__ x, const int* __restrict__ eidx,
                  const float* __restrict__ W0, const float* __restrict__ b0,
                  const float* __restrict__ W1, const float* __restrict__ b1,
                  const float* __restrict__ W2, const float* __restrict__ b2,
                  const float* __restrict__ W3, const float* __restrict__ b3,
                  const float* __restrict__ C1w, const float* __restrict__ C1b,
                  const float* __restrict__ C2w, const float* __restrict__ C2b,
                  const float* __restrict__ L1w, const float* __restrict__ L1b,
                  const float* __restrict__ L2w, const float* __restrict__ L2b,
                  float* __restrict__ out) {
    // LDS budget ~36.4 KB -> 4 blocks/CU (16 waves/CU, 50% occupancy).
    // Edge-setup arrays are dead once the CSR is built; the post-GCN tail
    // buffers union with them.
    __shared__ __align__(16) float lat[M][LATS];   // h1|h2|h3|h4 concat
    __shared__ float tbuf[M][H];                   // pre-aggregation h@W
    __shared__ union U {
        struct { int ls[EPG]; int ld[EPG]; } setup;
        struct {
            float z1[16][KTOP];
            float pbuf[16][15];
            float z2[352];
            float d1[128];
            float red[256];
            int   ord[M];
        } post;
    } u;
    __shared__ int   csr_off[M + 1], cursor[M];
    __shared__ int   csr_src[EPG];
    __shared__ float csr_nrm[EPG];
    __shared__ int   degi[M];
    __shared__ float dinv[M];

    const int g = blockIdx.x;
    const int tid = threadIdx.x;
    const int nbase = g * M;
    const int ebase = g * EPG;
    const float* xg = x + (size_t)nbase * F_IN;

    // ---- degrees (in-degree + self loop) ----
    if (tid < M) degi[tid] = 1;
    __syncthreads();
    for (int e = tid; e < EPG; e += NTHREADS) {
        int s = eidx[ebase + e] - nbase;
        int d = eidx[E_TOTAL + ebase + e] - nbase;
        u.setup.ls[e] = s; u.setup.ld[e] = d;
        atomicAdd(&degi[d], 1);
    }
    __syncthreads();
    if (tid < M) dinv[tid] = rsqrtf((float)degi[tid]);
    // ---- CSR offsets via wave-0 shuffle scan ----
    if (tid < 64) {
        int cnt = (tid < M) ? (degi[tid] - 1) : 0;
        int incl = cnt;
#pragma unroll
        for (int off = 1; off < 64; off <<= 1) {
            int nv = __shfl_up(incl, off);
            if (tid >= off) incl += nv;
        }
        if (tid < M) { csr_off[tid] = incl - cnt; cursor[tid] = incl - cnt; }
        if (tid == M - 1) csr_off[M] = incl;
    }
    __syncthreads();
    // ---- CSR fill (by dst), norm computed on the fly ----
    for (int e = tid; e < EPG; e += NTHREADS) {
        int s = u.setup.ls[e], d = u.setup.ld[e];
        float nr = dinv[s] * dinv[d];
        int pos = atomicAdd(&cursor[d], 1);
        csr_src[pos] = s;
        csr_nrm[pos] = nr;
    }
    __syncthreads();

    // ---- GCN layer 1: x[50,128] (global) -> lat[:,0:32] ----
    gcn_matmul<F_IN>(xg, F_IN, W0, tbuf, tid);
    __syncthreads();
    gcn_agg(tbuf, b0, lat, 0, dinv, csr_off, csr_src, csr_nrm, tid);
    __syncthreads();
    // ---- layer 2: lat[:,0:32] -> lat[:,32:64] ----
    gcn_matmul<H>(&lat[0][0], LATS, W1, tbuf, tid);
    __syncthreads();
    gcn_agg(tbuf, b1, lat, 32, dinv, csr_off, csr_src, csr_nrm, tid);
    __syncthreads();
    // ---- layer 3: lat[:,32:64] -> lat[:,64:96] ----
    gcn_matmul<H>(&lat[0][32], LATS, W2, tbuf, tid);
    __syncthreads();
    gcn_agg(tbuf, b2, lat, 64, dinv, csr_off, csr_src, csr_nrm, tid);
    __syncthreads();
    // ---- layer 4 (H -> 1): lat[:,64:96] -> lat[:,96] ----
    if (tid < M) {
        float acc = 0.f;
        for (int k = 0; k < H; k++) acc += lat[tid][64 + k] * W3[k];
        tbuf[tid][0] = acc;
    }
    __syncthreads();
    if (tid < M) {
        float acc = tbuf[tid][0] * dinv[tid] * dinv[tid];
        int e0 = csr_off[tid], e1 = csr_off[tid + 1];
        for (int e = e0; e < e1; e++)
            acc += tbuf[csr_src[e]][0] * csr_nrm[e];
        lat[tid][96] = tanhf(acc + b3[0]);
    }
    __syncthreads();

    // ---- sort-pool: stable descending rank over lat[:,96] ----
    if (tid < M) {
        float v = lat[tid][96];
        int r = 0;
        for (int jj = 0; jj < M; jj++) {
            float vj = lat[jj][96];
            r += (vj > v) || (vj == v && jj < tid);
        }
        u.post.ord[r] = tid;
    }
    __syncthreads();

    // ---- Conv1d(1,16,97,stride 97) + ReLU: z1[c][t] ----
    for (int idx = tid; idx < 16 * KTOP; idx += NTHREADS) {
        int c = idx / KTOP, t = idx - c * KTOP;
        const float* row = lat[u.post.ord[t]];
        float acc = 0.f;
        for (int d = 0; d < DLAT; d++) acc += row[d] * C1w[c * DLAT + d];
        acc += C1b[c];
        u.post.z1[c][t] = fmaxf(acc, 0.f);
    }
    __syncthreads();

    // ---- MaxPool1d(2,2) ----
    for (int idx = tid; idx < 16 * 15; idx += NTHREADS) {
        int c = idx / 15, t = idx - c * 15;
        u.post.pbuf[c][t] = fmaxf(u.post.z1[c][2 * t], u.post.z1[c][2 * t + 1]);
    }
    __syncthreads();

    // ---- Conv1d(16,32,5) + ReLU, flatten f = o*11 + t ----
    for (int idx = tid; idx < 352; idx += NTHREADS) {
        int o = idx / 11, t = idx - o * 11;
        float acc = C2b[o];
        for (int i = 0; i < 16; i++) {
#pragma unroll
            for (int k = 0; k < 5; k++)
                acc += u.post.pbuf[i][t + k] * C2w[(o * 16 + i) * 5 + k];
        }
        u.post.z2[idx] = fmaxf(acc, 0.f);
    }
    __syncthreads();

    // ---- Dense 352 -> 128 + ReLU (split across all 256 threads) ----
    {
        int jj = tid & 127, half = tid >> 7;
        float acc = (half == 0) ? L1b[jj] : 0.f;
        int f0 = half * 176;
        for (int f = f0; f < f0 + 176; f++)
            acc += u.post.z2[f] * L1w[f * 128 + jj];
        u.post.red[tid] = acc;
    }
    __syncthreads();
    if (tid < 128)
        u.post.d1[tid] = fmaxf(u.post.red[tid] + u.post.red[tid + 128], 0.f);
    __syncthreads();

    // ---- Dense 128 -> 1, wave-reduce ----
    if (tid < 128) u.post.red[tid] = u.post.d1[tid] * L2w[tid];
    __syncthreads();
    if (tid < 64) {
        float v = u.post.red[tid] + u.post.red[tid + 64];
#pragma unroll
        for (int off = 32; off >= 1; off >>= 1)
            v += __shfl_down(v, off);
        if (tid == 0) out[g] = v + L2b[0];
    }
}

extern "C" void kernel_launch(void* const* d_in, const int* in_sizes, int n_in,
                              void* d_out, int out_size, void* d_ws, size_t ws_size,
                              hipStream_t stream) {
    const float* x    = (const float*)d_in[0];
    const int*   eidx = (const int*)d_in[1];
    // d_in[2] (batch) unused: graphs are contiguous equal-size blocks
    dgcnn_kernel<<<NG, NTHREADS, 0, stream>>>(
        x, eidx,
        (const float*)d_in[3],  (const float*)d_in[4],
        (const float*)d_in[5],  (const float*)d_in[6],
        (const float*)d_in[7],  (const float*)d_in[8],
        (const float*)d_in[9],  (const float*)d_in[10],
        (const float*)d_in[11], (const float*)d_in[12],
        (const float*)d_in[13], (const float*)d_in[14],
        (const float*)d_in[15], (const float*)d_in[16],
        (const float*)d_in[17], (const float*)d_in[18],
        (float*)d_out);
}